// Round 1
// baseline (3961.088 us; speedup 1.0000x reference)
//
#include <hip/hip_runtime.h>

#define BB 4
#define TT 12
#define NN 10000
#define DD 2
#define EE 320000
#define HH 64
#define NPREDD 12
#define TD (TT*DD)   // 24

// ---------------- CSR build (keyed by dst; gather from src) ----------------
__global__ void hist_kernel(const int* __restrict__ dstv, int* __restrict__ deg) {
    int e = blockIdx.x*256 + threadIdx.x;
    if (e < EE) atomicAdd(&deg[dstv[e]], 1);
}

__global__ void scan_kernel(const int* __restrict__ deg, int* __restrict__ row_ptr,
                            int* __restrict__ cursor) {
    __shared__ int part[1024];
    int tid = threadIdx.x;
    const int CH = 10;                 // 1000 threads * 10 = 10000 nodes
    int start = tid*CH;
    int s = 0;
    if (start < NN)
        for (int i=0;i<CH;i++) s += deg[start+i];
    part[tid] = s;
    __syncthreads();
    if (tid == 0) {
        int acc = 0;
        for (int i=0;i<1024;i++){ int v=part[i]; part[i]=acc; acc+=v; }
        row_ptr[NN] = acc;
    }
    __syncthreads();
    if (start < NN) {
        int acc = part[tid];
        for (int i=0;i<CH;i++){ int idx=start+i; row_ptr[idx]=acc; cursor[idx]=acc; acc+=deg[idx]; }
    }
}

__global__ void fill_kernel(const int* __restrict__ srcv, const int* __restrict__ dstv,
                            const float* __restrict__ ew, int* __restrict__ cursor,
                            int2* __restrict__ csr) {
    int e = blockIdx.x*256 + threadIdx.x;
    if (e < EE) {
        int d = dstv[e];
        int pos = atomicAdd(&cursor[d], 1);
        csr[pos] = make_int2(srcv[e], __float_as_int(ew[e]));
    }
}

// ---------------- x transpose: [B,T,N,D] -> [B,N,T*D] ----------------
__global__ void transpose_x(const float* __restrict__ x, float* __restrict__ xT) {
    int idx = blockIdx.x*256 + threadIdx.x;
    if (idx >= BB*NN*TD) return;
    int d = idx & 1;
    int t = (idx >> 1) % TT;
    int n = (idx / TD) % NN;
    int b = idx / (NN*TD);
    xT[idx] = x[(((size_t)b*TT + t)*NN + n)*DD + d];
}

// ---------------- AX = A @ x_t for all t, layout [B,N,T*D] ----------------
__global__ void ax_gather(const float* __restrict__ xT, const int* __restrict__ row_ptr,
                          const int2* __restrict__ csr, float* __restrict__ AX) {
    int g = blockIdx.x*256 + threadIdx.x;
    int wave = g >> 6, lane = g & 63;
    if (wave >= BB*NN) return;
    int b = wave / NN, n = wave - b*NN;
    const float* xb = xT + (size_t)b*NN*TD;
    float acc = 0.f;
    int e1 = row_ptr[n+1];
    for (int e = row_ptr[n]; e < e1; ++e) {
        int2 sw = csr[e];
        if (lane < TD) acc += __int_as_float(sw.y) * xb[sw.x*TD + lane];
    }
    if (lane < TD) AX[(size_t)wave*TD + lane] = acc;
}

// ---------------- W1sum[k] = W1[k][:64] + W1[k][64:] ----------------
__global__ void w1sum_kernel(const float* __restrict__ W1, float* __restrict__ W1s) {
    int i = blockIdx.x*256 + threadIdx.x;
    if (i < 8192) {
        int k = i >> 12, r = (i >> 6) & 63, c = i & 63;
        W1s[i] = W1[(k*128 + r)*64 + c] + W1[(k*128 + 64 + r)*64 + c];
    }
}

// ---------------- fused layer: gather-propagate + both GEMMs + bias + relu ----------------
// L0==1: h_out = relu(x_t@W0[0][:2] + h_in@W0[0][2:] + AX_t@W0[1][:2] + (A@h_in)@W0[1][2:] + b)
// L0==0: h_out = relu(h_in@W[0] + (A@h_in)@W[1] + b)   (W = W1sum)
template<int L0>
__global__ __launch_bounds__(256)
void layer_kernel(const float* __restrict__ h_in,
                  const float* __restrict__ x,
                  const float* __restrict__ AX,
                  const float* __restrict__ W,
                  const float* __restrict__ bias,
                  const int* __restrict__ row_ptr,
                  const int2* __restrict__ csr,
                  float* __restrict__ h_out,
                  int t)
{
    __shared__ float sWa[4096];
    __shared__ float sWb[4096];
    __shared__ float sWx[256];
    __shared__ float sBias[64];
    __shared__ float sRow[4][2][64];

    int tid = threadIdx.x;
    if (L0) {
        for (int i=tid; i<4096; i+=256) { sWa[i] = W[128+i]; sWb[i] = W[4352+i]; }
        if (tid < 128) { sWx[tid] = W[tid]; sWx[128+tid] = W[4224+tid]; }
    } else {
        for (int i=tid; i<4096; i+=256) { sWa[i] = W[i]; sWb[i] = W[4096+i]; }
    }
    if (tid < 64) sBias[tid] = bias[tid];
    __syncthreads();

    int wave = tid >> 6, lane = tid & 63;
    // XCD-friendly mapping: batch from low bits of blockIdx so each XCD's
    // gather working set is (mostly) a single batch's h (2.56 MB < 4 MB L2).
    int b = blockIdx.x & 3;
    int chunk = blockIdx.x >> 2;       // 0..624
    const float* hb = h_in + (size_t)b*NN*HH;
    float* ho = h_out + (size_t)b*NN*HH;

    for (int i=0;i<4;i++) {
        int n = chunk*16 + wave*4 + i;
        float hv = hb[(size_t)n*HH + lane];
        sRow[wave][0][lane] = hv;
        float acc = 0.f;
        int e1 = row_ptr[n+1];
        for (int e = row_ptr[n]; e < e1; ++e) {
            int2 sw = csr[e];
            acc += __int_as_float(sw.y) * hb[(size_t)sw.x*HH + lane];
        }
        sRow[wave][1][lane] = acc;

        float out = sBias[lane];
        if (L0) {
            const float2 xv  = *(const float2*)(x  + (((size_t)b*TT + t)*NN + n)*DD);
            const float2 axv = *(const float2*)(AX + ((size_t)b*NN + n)*TD + t*DD);
            out += xv.x*sWx[lane] + xv.y*sWx[64+lane] + axv.x*sWx[128+lane] + axv.y*sWx[192+lane];
        }
        #pragma unroll
        for (int j=0;j<64;j++) {
            out = fmaf(sRow[wave][0][j], sWa[j*64+lane], out);
            out = fmaf(sRow[wave][1][j], sWb[j*64+lane], out);
        }
        out = fmaxf(out, 0.f);
        ho[(size_t)n*HH + lane] = out;
    }
}

// ---------------- output: out[b,p,n,0] = h[b,n,:]@Wp + bp ----------------
__global__ void out_kernel(const float* __restrict__ h, const float* __restrict__ Wp,
                           const float* __restrict__ bp, float* __restrict__ outp) {
    int g = blockIdx.x*256 + threadIdx.x;
    int wave = g >> 6, lane = g & 63;
    if (wave >= BB*NN) return;
    int b = wave / NN, n = wave - b*NN;
    float v = h[(size_t)wave*HH + lane] * Wp[lane];
    for (int off=32; off; off>>=1) v += __shfl_down(v, off);
    v = __shfl(v, 0) + bp[0];
    if (lane < NPREDD) outp[((size_t)b*NPREDD + lane)*NN + n] = v;
}

extern "C" void kernel_launch(void* const* d_in, const int* in_sizes, int n_in,
                              void* d_out, int out_size, void* d_ws, size_t ws_size,
                              hipStream_t stream) {
    const float* x   = (const float*)d_in[0];
    const int*   ei  = (const int*)d_in[1];
    const float* ew  = (const float*)d_in[2];
    const float* W0  = (const float*)d_in[3];
    const float* b0  = (const float*)d_in[4];
    const float* W1  = (const float*)d_in[5];
    const float* b1  = (const float*)d_in[6];
    const float* Wp  = (const float*)d_in[7];
    const float* bp  = (const float*)d_in[8];
    float* outp = (float*)d_out;

    char* ws = (char*)d_ws;
    size_t off = 0;
    auto alloc = [&](size_t bytes) { void* p = ws + off; off = (off + bytes + 255) & ~(size_t)255; return p; };
    float* h    = (float*)alloc((size_t)BB*NN*HH*4);
    float* h1   = (float*)alloc((size_t)BB*NN*HH*4);
    float* xT   = (float*)alloc((size_t)BB*NN*TD*4);
    float* AX   = (float*)alloc((size_t)BB*NN*TD*4);
    float* W1s  = (float*)alloc(2*64*64*4);
    int2*  csr  = (int2*)alloc((size_t)EE*8);
    int* row_ptr= (int*)alloc((NN+1)*4);
    int* deg    = (int*)alloc(NN*4);
    int* cursor = (int*)alloc(NN*4);

    const int* srcv = ei;
    const int* dstv = ei + EE;

    hipMemsetAsync(deg, 0, NN*4, stream);
    hipMemsetAsync(h, 0, (size_t)BB*NN*HH*4, stream);

    hist_kernel<<<(EE+255)/256, 256, 0, stream>>>(dstv, deg);
    scan_kernel<<<1, 1024, 0, stream>>>(deg, row_ptr, cursor);
    fill_kernel<<<(EE+255)/256, 256, 0, stream>>>(srcv, dstv, ew, cursor, csr);
    transpose_x<<<(BB*NN*TD+255)/256, 256, 0, stream>>>(x, xT);
    ax_gather<<<(BB*NN*64+255)/256, 256, 0, stream>>>(xT, row_ptr, csr, AX);
    w1sum_kernel<<<32, 256, 0, stream>>>(W1, W1s);

    for (int t=0; t<TT; ++t) {
        layer_kernel<1><<<2500, 256, 0, stream>>>(h,  x, AX, W0,  b0, row_ptr, csr, h1, t);
        layer_kernel<0><<<2500, 256, 0, stream>>>(h1, nullptr, nullptr, W1s, b1, row_ptr, csr, h, 0);
    }
    out_kernel<<<(BB*NN*64+255)/256, 256, 0, stream>>>(h, Wp, bp, outp);
}

// Round 2
// 2021.995 us; speedup vs baseline: 1.9590x; 1.9590x over previous
//
#include <hip/hip_runtime.h>

#define BB 4
#define TT 12
#define NN 10000
#define DD 2
#define EE 320000
#define HH 64
#define NPREDD 12
#define TD (TT*DD)   // 24

__device__ __forceinline__ float bcast(float v, int j) {
    return __int_as_float(__builtin_amdgcn_readlane(__float_as_int(v), j));
}

// ---------------- CSR build (keyed by dst; gather from src) ----------------
__global__ void hist_kernel(const int* __restrict__ dstv, int* __restrict__ deg) {
    int e = blockIdx.x*256 + threadIdx.x;
    if (e < EE) atomicAdd(&deg[dstv[e]], 1);
}

__global__ void scan_kernel(const int* __restrict__ deg, int* __restrict__ row_ptr,
                            int* __restrict__ cursor) {
    __shared__ int part[1024];
    int tid = threadIdx.x;
    const int CH = 10;                 // 1000 threads * 10 = 10000 nodes
    int start = tid*CH;
    int s = 0;
    if (start < NN)
        for (int i=0;i<CH;i++) s += deg[start+i];
    part[tid] = s;
    __syncthreads();
    if (tid == 0) {
        int acc = 0;
        for (int i=0;i<1024;i++){ int v=part[i]; part[i]=acc; acc+=v; }
        row_ptr[NN] = acc;
    }
    __syncthreads();
    if (start < NN) {
        int acc = part[tid];
        for (int i=0;i<CH;i++){ int idx=start+i; row_ptr[idx]=acc; cursor[idx]=acc; acc+=deg[idx]; }
    }
}

__global__ void fill_kernel(const int* __restrict__ srcv, const int* __restrict__ dstv,
                            const float* __restrict__ ew, int* __restrict__ cursor,
                            int2* __restrict__ csr) {
    int e = blockIdx.x*256 + threadIdx.x;
    if (e < EE) {
        int d = dstv[e];
        int pos = atomicAdd(&cursor[d], 1);
        csr[pos] = make_int2(srcv[e], __float_as_int(ew[e]));
    }
}

// ---------------- x transpose: [B,T,N,D] -> [B,N,T*D] ----------------
__global__ void transpose_x(const float* __restrict__ x, float* __restrict__ xT) {
    int idx = blockIdx.x*256 + threadIdx.x;
    if (idx >= BB*NN*TD) return;
    int d = idx & 1;
    int t = (idx >> 1) % TT;
    int n = (idx / TD) % NN;
    int b = idx / (NN*TD);
    xT[idx] = x[(((size_t)b*TT + t)*NN + n)*DD + d];
}

// ---------------- AX = A @ x_t for all t, layout [B,N,T*D] ----------------
__global__ void ax_gather(const float* __restrict__ xT, const int* __restrict__ row_ptr,
                          const int2* __restrict__ csr, float* __restrict__ AX) {
    int g = blockIdx.x*256 + threadIdx.x;
    int wave = g >> 6, lane = g & 63;
    if (wave >= BB*NN) return;
    int b = wave / NN, n = wave - b*NN;
    const float* xb = xT + (size_t)b*NN*TD;
    float acc = 0.f;
    int e1 = row_ptr[n+1];
    for (int e = row_ptr[n]; e < e1; ++e) {
        int2 sw = csr[e];
        if (lane < TD) acc += __int_as_float(sw.y) * xb[sw.x*TD + lane];
    }
    if (lane < TD) AX[(size_t)wave*TD + lane] = acc;
}

// ---------------- W1sum[k] = W1[k][:64] + W1[k][64:] ----------------
__global__ void w1sum_kernel(const float* __restrict__ W1, float* __restrict__ W1s) {
    int i = blockIdx.x*256 + threadIdx.x;
    if (i < 8192) {
        int k = i >> 12, r = (i >> 6) & 63, c = i & 63;
        W1s[i] = W1[(k*128 + r)*64 + c] + W1[(k*128 + 64 + r)*64 + c];
    }
}

// ---------------- fused layer: gather-propagate + both GEMMs + bias + relu ----------------
template<int L0>
__global__ __launch_bounds__(256)
void layer_kernel(const float* __restrict__ h_in,
                  const float* __restrict__ x,
                  const float* __restrict__ AX,
                  const float* __restrict__ W,
                  const float* __restrict__ bias,
                  const int* __restrict__ row_ptr,
                  const int2* __restrict__ csr,
                  float* __restrict__ h_out,
                  int t)
{
    __shared__ float sWa[4096];   // [j][out]
    __shared__ float sWb[4096];   // [j][out]
    __shared__ float sWx[256];
    __shared__ float sBias[64];

    int tid = threadIdx.x;
    if (L0) {
        for (int i=tid; i<4096; i+=256) { sWa[i] = W[128+i]; sWb[i] = W[4352+i]; }
        if (tid < 128) { sWx[tid] = W[tid]; sWx[128+tid] = W[4224+tid]; }
    } else {
        for (int i=tid; i<4096; i+=256) { sWa[i] = W[i]; sWb[i] = W[4096+i]; }
    }
    if (tid < 64) sBias[tid] = bias[tid];
    __syncthreads();

    int wave = tid >> 6, lane = tid & 63;
    int b = blockIdx.x & 3;          // batch -> XCD pair, keeps gather set in L2
    int chunk = blockIdx.x >> 2;     // 0..624
    const float* hb = h_in + (size_t)b*NN*HH;
    float* ho = h_out + (size_t)b*NN*HH;
    int n0 = chunk*16 + wave*4;

    float hv[4], ac[4];
    #pragma unroll
    for (int i=0;i<4;i++) {
        int n = n0 + i;
        hv[i] = hb[(size_t)n*HH + lane];
        float acc = 0.f;
        int e = row_ptr[n], e1 = row_ptr[n+1];
        // unrolled-by-8 gather: 8 csr loads then 8 independent row gathers in flight
        for (; e + 8 <= e1; e += 8) {
            int2 c0 = csr[e+0]; int2 c1 = csr[e+1]; int2 c2 = csr[e+2]; int2 c3 = csr[e+3];
            int2 c4 = csr[e+4]; int2 c5 = csr[e+5]; int2 c6 = csr[e+6]; int2 c7 = csr[e+7];
            float v0 = hb[(size_t)c0.x*HH + lane];
            float v1 = hb[(size_t)c1.x*HH + lane];
            float v2 = hb[(size_t)c2.x*HH + lane];
            float v3 = hb[(size_t)c3.x*HH + lane];
            float v4 = hb[(size_t)c4.x*HH + lane];
            float v5 = hb[(size_t)c5.x*HH + lane];
            float v6 = hb[(size_t)c6.x*HH + lane];
            float v7 = hb[(size_t)c7.x*HH + lane];
            acc = fmaf(__int_as_float(c0.y), v0, acc);
            acc = fmaf(__int_as_float(c1.y), v1, acc);
            acc = fmaf(__int_as_float(c2.y), v2, acc);
            acc = fmaf(__int_as_float(c3.y), v3, acc);
            acc = fmaf(__int_as_float(c4.y), v4, acc);
            acc = fmaf(__int_as_float(c5.y), v5, acc);
            acc = fmaf(__int_as_float(c6.y), v6, acc);
            acc = fmaf(__int_as_float(c7.y), v7, acc);
        }
        for (; e < e1; ++e) {
            int2 c = csr[e];
            acc = fmaf(__int_as_float(c.y), hb[(size_t)c.x*HH + lane], acc);
        }
        ac[i] = acc;
    }

    float out[4];
    #pragma unroll
    for (int i=0;i<4;i++) out[i] = sBias[lane];
    if (L0) {
        #pragma unroll
        for (int i=0;i<4;i++) {
            int n = n0 + i;
            const float2 xv  = *(const float2*)(x  + (((size_t)b*TT + t)*NN + n)*DD);
            const float2 axv = *(const float2*)(AX + ((size_t)b*NN + n)*TD + t*DD);
            out[i] += xv.x*sWx[lane] + xv.y*sWx[64+lane]
                    + axv.x*sWx[128+lane] + axv.y*sWx[192+lane];
        }
    }

    // 4-row-shared GEMM: each weight column read once; row values via readlane
    #pragma unroll
    for (int j=0;j<64;j++) {
        float wa = sWa[j*64 + lane];
        float wb = sWb[j*64 + lane];
        #pragma unroll
        for (int i=0;i<4;i++) {
            out[i] = fmaf(bcast(hv[i], j), wa, out[i]);
            out[i] = fmaf(bcast(ac[i], j), wb, out[i]);
        }
    }

    #pragma unroll
    for (int i=0;i<4;i++)
        ho[(size_t)(n0+i)*HH + lane] = fmaxf(out[i], 0.f);
}

// ---------------- output: out[b,p,n,0] = h[b,n,:]@Wp + bp ----------------
__global__ void out_kernel(const float* __restrict__ h, const float* __restrict__ Wp,
                           const float* __restrict__ bp, float* __restrict__ outp) {
    int g = blockIdx.x*256 + threadIdx.x;
    int wave = g >> 6, lane = g & 63;
    if (wave >= BB*NN) return;
    int b = wave / NN, n = wave - b*NN;
    float v = h[(size_t)wave*HH + lane] * Wp[lane];
    for (int off=32; off; off>>=1) v += __shfl_down(v, off);
    v = __shfl(v, 0) + bp[0];
    if (lane < NPREDD) outp[((size_t)b*NPREDD + lane)*NN + n] = v;
}

extern "C" void kernel_launch(void* const* d_in, const int* in_sizes, int n_in,
                              void* d_out, int out_size, void* d_ws, size_t ws_size,
                              hipStream_t stream) {
    const float* x   = (const float*)d_in[0];
    const int*   ei  = (const int*)d_in[1];
    const float* ew  = (const float*)d_in[2];
    const float* W0  = (const float*)d_in[3];
    const float* b0  = (const float*)d_in[4];
    const float* W1  = (const float*)d_in[5];
    const float* b1  = (const float*)d_in[6];
    const float* Wp  = (const float*)d_in[7];
    const float* bp  = (const float*)d_in[8];
    float* outp = (float*)d_out;

    char* ws = (char*)d_ws;
    size_t off = 0;
    auto alloc = [&](size_t bytes) { void* p = ws + off; off = (off + bytes + 255) & ~(size_t)255; return p; };
    float* h    = (float*)alloc((size_t)BB*NN*HH*4);
    float* h1   = (float*)alloc((size_t)BB*NN*HH*4);
    float* xT   = (float*)alloc((size_t)BB*NN*TD*4);
    float* AX   = (float*)alloc((size_t)BB*NN*TD*4);
    float* W1s  = (float*)alloc(2*64*64*4);
    int2*  csr  = (int2*)alloc((size_t)EE*8);
    int* row_ptr= (int*)alloc((NN+1)*4);
    int* deg    = (int*)alloc(NN*4);
    int* cursor = (int*)alloc(NN*4);

    const int* srcv = ei;
    const int* dstv = ei + EE;

    hipMemsetAsync(deg, 0, NN*4, stream);
    hipMemsetAsync(h, 0, (size_t)BB*NN*HH*4, stream);

    hist_kernel<<<(EE+255)/256, 256, 0, stream>>>(dstv, deg);
    scan_kernel<<<1, 1024, 0, stream>>>(deg, row_ptr, cursor);
    fill_kernel<<<(EE+255)/256, 256, 0, stream>>>(srcv, dstv, ew, cursor, csr);
    transpose_x<<<(BB*NN*TD+255)/256, 256, 0, stream>>>(x, xT);
    ax_gather<<<(BB*NN*64+255)/256, 256, 0, stream>>>(xT, row_ptr, csr, AX);
    w1sum_kernel<<<32, 256, 0, stream>>>(W1, W1s);

    for (int t=0; t<TT; ++t) {
        layer_kernel<1><<<2500, 256, 0, stream>>>(h,  x, AX, W0,  b0, row_ptr, csr, h1, t);
        layer_kernel<0><<<2500, 256, 0, stream>>>(h1, nullptr, nullptr, W1s, b1, row_ptr, csr, h, 0);
    }
    out_kernel<<<(BB*NN*64+255)/256, 256, 0, stream>>>(h, Wp, bp, outp);
}